// Round 2
// baseline (359.870 us; speedup 1.0000x reference)
//
#include <hip/hip_runtime.h>

typedef __bf16 bf16;
typedef __bf16 bf16x4v __attribute__((ext_vector_type(4)));
typedef __bf16 bf16x8 __attribute__((ext_vector_type(8)));
typedef float f32x4 __attribute__((ext_vector_type(4)));

#define MFMA16(a, b, c) __builtin_amdgcn_mfma_f32_16x16x32_bf16((a), (b), (c), 0, 0, 0)

#define SEQ 2048
#define DM 1024
#define NH 16

// ---------------------------------------------------------------------------
// fp32 -> bf16 convert (inputs arrive as float32 per the reference dtypes).
// ---------------------------------------------------------------------------
__global__ __launch_bounds__(256) void cvt_bf16(const float* __restrict__ s,
                                                bf16* __restrict__ d, int n4) {
    const int i = blockIdx.x * 256 + threadIdx.x;
    if (i < n4) {
        const float4 v = ((const float4*)s)[i];
        bf16x4v o;
        o.x = (bf16)v.x; o.y = (bf16)v.y; o.z = (bf16)v.z; o.w = (bf16)v.w;
        ((bf16x4v*)d)[i] = o;
    }
}

// ---------------------------------------------------------------------------
// NT GEMM: C[M,N] = A[M,K] * B[N,K]^T, bf16 in, fp32 accum, CT out.
// Block tile 128x128, BK=32, 256 threads = 4 waves, each wave 64x64 (4x4 MFMA).
// LDS rows padded to 40 bf16 (80B = 20-bank shift -> 2-way conflicts, free).
// ---------------------------------------------------------------------------
template <typename CT>
__global__ __launch_bounds__(256) void gemm_nt(const bf16* __restrict__ A,
                                               const bf16* __restrict__ B,
                                               CT* __restrict__ C,
                                               int M, int N, int K) {
    __shared__ bf16 As[128 * 40];
    __shared__ bf16 Bs[128 * 40];

    const int tid  = threadIdx.x;
    const int lane = tid & 63;
    const int w    = tid >> 6;
    const int quad = lane >> 4;
    const int l15  = lane & 15;
    const int wm   = (w & 1) * 64;
    const int wn   = (w >> 1) * 64;
    const int rowBase = blockIdx.y * 128;
    const int colBase = blockIdx.x * 128;

    const int srow = tid >> 2;  // 0..63
    const int sseg = tid & 3;   // 0..3 (8 bf16 each)

    f32x4 acc[4][4] = {};

    for (int k0 = 0; k0 < K; k0 += 32) {
        __syncthreads();
#pragma unroll
        for (int r = 0; r < 2; ++r) {
            const int row = srow + r * 64;
            bf16x8 av = *(const bf16x8*)(A + (size_t)(rowBase + row) * K + k0 + sseg * 8);
            *(bf16x8*)(As + row * 40 + sseg * 8) = av;
            bf16x8 bv = *(const bf16x8*)(B + (size_t)(colBase + row) * K + k0 + sseg * 8);
            *(bf16x8*)(Bs + row * 40 + sseg * 8) = bv;
        }
        __syncthreads();

        bf16x8 af[4], bfr[4];
#pragma unroll
        for (int i = 0; i < 4; ++i) {
            af[i]  = *(const bf16x8*)(As + (wm + i * 16 + l15) * 40 + quad * 8);
            bfr[i] = *(const bf16x8*)(Bs + (wn + i * 16 + l15) * 40 + quad * 8);
        }
#pragma unroll
        for (int i = 0; i < 4; ++i)
#pragma unroll
            for (int j = 0; j < 4; ++j)
                acc[i][j] = MFMA16(af[i], bfr[j], acc[i][j]);
    }

#pragma unroll
    for (int i = 0; i < 4; ++i)
#pragma unroll
        for (int j = 0; j < 4; ++j)
#pragma unroll
            for (int r = 0; r < 4; ++r) {
                const int row = rowBase + wm + i * 16 + quad * 4 + r;
                const int col = colBase + wn + j * 16 + l15;
                C[(size_t)row * N + col] = (CT)acc[i][j][r];
            }
}

// ---------------------------------------------------------------------------
// Causal flash attention. qkv layout: (B*S, 3*DM) row-major bf16; head h uses
// cols [h*64, h*64+64) of each 1024-chunk (Q at 0, K at 1024, V at 2048).
// Block = (qtile of 64 rows, b*h). 4 waves x 16 q-rows. K-tile = 32 keys.
// ---------------------------------------------------------------------------
__global__ __launch_bounds__(256) void attn_fwd(const bf16* __restrict__ qkv,
                                                bf16* __restrict__ ao) {
    __shared__ bf16 Kt[32 * 72];       // K tile, rows padded to 72
    __shared__ bf16 Vt[64 * 40];       // V tile transposed [d][key], padded to 40
    __shared__ bf16 Pw[4][16 * 40];    // per-wave P round-trip, padded to 40

    const int tid  = threadIdx.x;
    const int lane = tid & 63;
    const int w    = tid >> 6;
    const int quad = lane >> 4;
    const int l15  = lane & 15;
    const int qtile = blockIdx.x;
    const int bh    = blockIdx.y;
    const int b = bh >> 4, h = bh & 15;
    const int qbase  = qtile * 64;
    const int wqbase = qbase + w * 16;

    const size_t rs = 3 * DM;
    const bf16* base = qkv + (size_t)b * SEQ * rs;

    // Q fragments (stay in registers): A[m=l15][k=quad*8+j], d in [0,64)
    const bf16* qp = base + (size_t)(wqbase + l15) * rs + h * 64 + quad * 8;
    const bf16x8 q_lo = *(const bf16x8*)(qp);
    const bf16x8 q_hi = *(const bf16x8*)(qp + 32);

    f32x4 o[4] = {};
    float mi[4], li[4];
#pragma unroll
    for (int r = 0; r < 4; ++r) { mi[r] = -1e30f; li[r] = 0.f; }

    const int nkt  = (qbase + 64) >> 5;
    const int srow = tid >> 3;  // 0..31
    const int sseg = tid & 7;   // 0..7

    for (int kt = 0; kt < nkt; ++kt) {
        const int k0 = kt * 32;
        __syncthreads();
        {
            bf16x8 kv = *(const bf16x8*)(base + (size_t)(k0 + srow) * rs + DM + h * 64 + sseg * 8);
            *(bf16x8*)(Kt + srow * 72 + sseg * 8) = kv;
            bf16x8 vv = *(const bf16x8*)(base + (size_t)(k0 + srow) * rs + 2 * DM + h * 64 + sseg * 8);
#pragma unroll
            for (int j = 0; j < 8; ++j) Vt[(sseg * 8 + j) * 40 + srow] = vv[j];
        }
        __syncthreads();

        if (k0 <= wqbase + 15) {  // wave-uniform: some column unmasked
            f32x4 s[2];
#pragma unroll
            for (int t = 0; t < 2; ++t) {
                bf16x8 k_lo = *(const bf16x8*)(Kt + (t * 16 + l15) * 72 + quad * 8);
                bf16x8 k_hi = *(const bf16x8*)(Kt + (t * 16 + l15) * 72 + 32 + quad * 8);
                f32x4 z = {};
                z = MFMA16(q_lo, k_lo, z);
                z = MFMA16(q_hi, k_hi, z);
                s[t] = z;
            }
            float p0[4], p1[4], alpha[4];
#pragma unroll
            for (int r = 0; r < 4; ++r) {
                const int qrow = wqbase + quad * 4 + r;
                float s0 = s[0][r] * 0.125f;
                float s1 = s[1][r] * 0.125f;
                if (k0 + l15 > qrow)      s0 = -1e30f;
                if (k0 + 16 + l15 > qrow) s1 = -1e30f;
                float mx = fmaxf(s0, s1);
#pragma unroll
                for (int d = 1; d < 16; d <<= 1) mx = fmaxf(mx, __shfl_xor(mx, d));
                const float mnew = fmaxf(mi[r], mx);
                alpha[r] = __expf(mi[r] - mnew);
                p0[r] = __expf(s0 - mnew);
                p1[r] = __expf(s1 - mnew);
                float rsum = p0[r] + p1[r];
#pragma unroll
                for (int d = 1; d < 16; d <<= 1) rsum += __shfl_xor(rsum, d);
                li[r] = li[r] * alpha[r] + rsum;
                mi[r] = mnew;
            }
            bf16* P = &Pw[w][0];
#pragma unroll
            for (int r = 0; r < 4; ++r) {
#pragma unroll
                for (int db = 0; db < 4; ++db) o[db][r] *= alpha[r];
                P[(quad * 4 + r) * 40 + l15]      = (bf16)p0[r];
                P[(quad * 4 + r) * 40 + 16 + l15] = (bf16)p1[r];
            }
            asm volatile("s_waitcnt lgkmcnt(0)" ::: "memory");
            const bf16x8 pf = *(const bf16x8*)(P + l15 * 40 + quad * 8);
#pragma unroll
            for (int db = 0; db < 4; ++db) {
                bf16x8 vf = *(const bf16x8*)(Vt + (db * 16 + l15) * 40 + quad * 8);
                o[db] = MFMA16(pf, vf, o[db]);
            }
        }
    }

    bf16* aop = ao + (size_t)b * SEQ * DM + (size_t)h * 64;
#pragma unroll
    for (int r = 0; r < 4; ++r) {
        const float inv = 1.f / li[r];
        const int qrow = wqbase + quad * 4 + r;
#pragma unroll
        for (int db = 0; db < 4; ++db)
            aop[(size_t)qrow * DM + db * 16 + l15] = (bf16)(o[db][r] * inv);
    }
}

// ---------------------------------------------------------------------------
extern "C" void kernel_launch(void* const* d_in, const int* in_sizes, int n_in,
                              void* d_out, int out_size, void* d_ws, size_t ws_size,
                              hipStream_t stream) {
    const float* X    = (const float*)d_in[0];   // (2*2048, 1024) fp32
    const float* Wqkv = (const float*)d_in[1];   // (3072, 1024)   fp32
    const float* Wout = (const float*)d_in[2];   // (1024, 1024)   fp32
    float* out = (float*)d_out;                  // (2*2048, 1024) fp32

    const int M = 2 * SEQ;  // 4096
    const size_t nX    = (size_t)M * DM;          // 4M
    const size_t nWqkv = (size_t)3 * DM * DM;     // 3M
    const size_t nWout = (size_t)DM * DM;         // 1M
    const size_t nQKV  = (size_t)M * 3 * DM;      // 12M
    const size_t nAO   = (size_t)M * DM;          // 4M

    if (ws_size < (nX + nWqkv + nWout + nQKV + nAO) * sizeof(bf16)) return;

    bf16* Xb    = (bf16*)d_ws;
    bf16* Wqkvb = Xb + nX;
    bf16* Woutb = Wqkvb + nWqkv;
    bf16* qkv   = Woutb + nWout;
    bf16* ao    = qkv + nQKV;

    // 0) fp32 -> bf16 converts
    cvt_bf16<<<dim3((int)(nX / 4 / 256)),    256, 0, stream>>>(X,    Xb,    (int)(nX / 4));
    cvt_bf16<<<dim3((int)(nWqkv / 4 / 256)), 256, 0, stream>>>(Wqkv, Wqkvb, (int)(nWqkv / 4));
    cvt_bf16<<<dim3((int)(nWout / 4 / 256)), 256, 0, stream>>>(Wout, Woutb, (int)(nWout / 4));

    // 1) QKV projection: (4096,1024) @ (3072,1024)^T -> (4096,3072) bf16
    gemm_nt<bf16><<<dim3(3 * DM / 128, M / 128), 256, 0, stream>>>(Xb, Wqkvb, qkv, M, 3 * DM, DM);
    // 2) causal attention -> (4096,1024) bf16 in (B,S,H,dk) flat layout
    attn_fwd<<<dim3(SEQ / 64, 2 * NH), 256, 0, stream>>>(qkv, ao);
    // 3) out projection: (4096,1024) @ (1024,1024)^T -> (4096,1024) fp32
    gemm_nt<float><<<dim3(DM / 128, M / 128), 256, 0, stream>>>(ao, Woutb, out, M, DM, DM);
}

// Round 3
// 194.413 us; speedup vs baseline: 1.8511x; 1.8511x over previous
//
#include <hip/hip_runtime.h>

typedef __bf16 bf16;
typedef __bf16 bf16x4v __attribute__((ext_vector_type(4)));
typedef __bf16 bf16x8 __attribute__((ext_vector_type(8)));
typedef float f32x4 __attribute__((ext_vector_type(4)));

#define MFMA16(a, b, c) __builtin_amdgcn_mfma_f32_16x16x32_bf16((a), (b), (c), 0, 0, 0)

#define SEQ 2048
#define DM 1024
#define NH 16

// ---------------------------------------------------------------------------
// fp32 -> bf16 convert
// ---------------------------------------------------------------------------
__global__ __launch_bounds__(256) void cvt_bf16(const float* __restrict__ s,
                                                bf16* __restrict__ d, int n4) {
    const int i = blockIdx.x * 256 + threadIdx.x;
    if (i < n4) {
        const float4 v = ((const float4*)s)[i];
        bf16x4v o;
        o.x = (bf16)v.x; o.y = (bf16)v.y; o.z = (bf16)v.z; o.w = (bf16)v.w;
        ((bf16x4v*)d)[i] = o;
    }
}

// ---------------------------------------------------------------------------
// Generic NT GEMM: C[M,N] = A[M,K] * B[N,K]^T  (used for out-projection)
// ---------------------------------------------------------------------------
template <typename CT>
__global__ __launch_bounds__(256) void gemm_nt(const bf16* __restrict__ A,
                                               const bf16* __restrict__ B,
                                               CT* __restrict__ C,
                                               int M, int N, int K) {
    __shared__ bf16 As[128 * 40];
    __shared__ bf16 Bs[128 * 40];

    const int tid = threadIdx.x;
    const int lane = tid & 63, w = tid >> 6;
    const int quad = lane >> 4, l15 = lane & 15;
    const int wm = (w & 1) * 64, wn = (w >> 1) * 64;
    const int rowBase = blockIdx.y * 128, colBase = blockIdx.x * 128;
    const int srow = tid >> 2, sseg = tid & 3;

    f32x4 acc[4][4] = {};

    for (int k0 = 0; k0 < K; k0 += 32) {
        __syncthreads();
#pragma unroll
        for (int r = 0; r < 2; ++r) {
            const int row = srow + r * 64;
            *(bf16x8*)(As + row * 40 + sseg * 8) =
                *(const bf16x8*)(A + (size_t)(rowBase + row) * K + k0 + sseg * 8);
            *(bf16x8*)(Bs + row * 40 + sseg * 8) =
                *(const bf16x8*)(B + (size_t)(colBase + row) * K + k0 + sseg * 8);
        }
        __syncthreads();

        bf16x8 af[4], bfr[4];
#pragma unroll
        for (int i = 0; i < 4; ++i) {
            af[i]  = *(const bf16x8*)(As + (wm + i * 16 + l15) * 40 + quad * 8);
            bfr[i] = *(const bf16x8*)(Bs + (wn + i * 16 + l15) * 40 + quad * 8);
        }
#pragma unroll
        for (int i = 0; i < 4; ++i)
#pragma unroll
            for (int j = 0; j < 4; ++j)
                acc[i][j] = MFMA16(af[i], bfr[j], acc[i][j]);
    }

#pragma unroll
    for (int i = 0; i < 4; ++i)
#pragma unroll
        for (int j = 0; j < 4; ++j)
#pragma unroll
            for (int r = 0; r < 4; ++r)
                C[(size_t)(rowBase + wm + i * 16 + quad * 4 + r) * N +
                  colBase + wn + j * 16 + l15] = (CT)acc[i][j][r];
}

// ---------------------------------------------------------------------------
// QKV GEMM: A=(4096,1024) X, B=(3072,1024) W. Q,K thirds -> qkbuf (M x 2048);
// V third -> TRANSPOSED store into vtg[(b*16+h)*64+d][s] (b64 per tile, free).
// ---------------------------------------------------------------------------
__global__ __launch_bounds__(256) void gemm_qkv(const bf16* __restrict__ A,
                                                const bf16* __restrict__ B,
                                                bf16* __restrict__ qkbuf,
                                                bf16* __restrict__ vtg) {
    __shared__ bf16 As[128 * 40];
    __shared__ bf16 Bs[128 * 40];

    const int K = DM, tid = threadIdx.x;
    const int lane = tid & 63, w = tid >> 6;
    const int quad = lane >> 4, l15 = lane & 15;
    const int wm = (w & 1) * 64, wn = (w >> 1) * 64;
    const int rowBase = blockIdx.y * 128, colBase = blockIdx.x * 128;
    const int srow = tid >> 2, sseg = tid & 3;

    f32x4 acc[4][4] = {};

    for (int k0 = 0; k0 < K; k0 += 32) {
        __syncthreads();
#pragma unroll
        for (int r = 0; r < 2; ++r) {
            const int row = srow + r * 64;
            *(bf16x8*)(As + row * 40 + sseg * 8) =
                *(const bf16x8*)(A + (size_t)(rowBase + row) * K + k0 + sseg * 8);
            *(bf16x8*)(Bs + row * 40 + sseg * 8) =
                *(const bf16x8*)(B + (size_t)(colBase + row) * K + k0 + sseg * 8);
        }
        __syncthreads();

        bf16x8 af[4], bfr[4];
#pragma unroll
        for (int i = 0; i < 4; ++i) {
            af[i]  = *(const bf16x8*)(As + (wm + i * 16 + l15) * 40 + quad * 8);
            bfr[i] = *(const bf16x8*)(Bs + (wn + i * 16 + l15) * 40 + quad * 8);
        }
#pragma unroll
        for (int i = 0; i < 4; ++i)
#pragma unroll
            for (int j = 0; j < 4; ++j)
                acc[i][j] = MFMA16(af[i], bfr[j], acc[i][j]);
    }

    if (colBase < 2 * DM) {
        // Q,K region: row store into qkbuf (row stride 2048)
#pragma unroll
        for (int i = 0; i < 4; ++i)
#pragma unroll
            for (int j = 0; j < 4; ++j)
#pragma unroll
                for (int r = 0; r < 4; ++r)
                    qkbuf[(size_t)(rowBase + wm + i * 16 + quad * 4 + r) * 2048 +
                          colBase + wn + j * 16 + l15] = (bf16)acc[i][j][r];
    } else {
        // V region: transposed store. col-2048 = h*64+d; vtg[(b*1024+col)][s]
#pragma unroll
        for (int i = 0; i < 4; ++i) {
            const int row0 = rowBase + wm + i * 16 + quad * 4;  // s, 4 consecutive
            const int b = row0 >> 11, s = row0 & 2047;
#pragma unroll
            for (int j = 0; j < 4; ++j) {
                const int col = colBase + wn + j * 16 + l15 - 2 * DM;  // 0..1023
                bf16x4v pk;
#pragma unroll
                for (int r = 0; r < 4; ++r) pk[r] = (bf16)acc[i][j][r];
                *(bf16x4v*)(vtg + (size_t)(b * DM + col) * SEQ + s) = pk;
            }
        }
    }
}

// ---------------------------------------------------------------------------
// Causal flash attention, S^T formulation.
// Block: 64 q-rows (4 waves x 16 q), K-tile 64. Per lane: q = lane&15.
// S^T tiles via MFMA(A=K, B=Q) -> row=key, col=q. Softmax rows live at fixed
// l15: local max/sum + 2 shuffles (xor16, xor32). PV as O^T = V^T . P^T.
// V^T comes pre-transposed from gemm_qkv (vtg).
// ---------------------------------------------------------------------------
__global__ __launch_bounds__(256) void attn_fwd(const bf16* __restrict__ qk,
                                                const bf16* __restrict__ vtg,
                                                bf16* __restrict__ ao) {
    __shared__ bf16 Ks[64 * 72];      // [key][d], stride 72 (144B, 16B-aligned)
    __shared__ bf16 Vts[64 * 72];     // [d][key]
    __shared__ bf16 Pt[4][16 * 72];   // per-wave P, [q][key]

    const int tid = threadIdx.x;
    const int lane = tid & 63, w = tid >> 6;
    const int quad = lane >> 4, l15 = lane & 15;
    const int bh = blockIdx.x;               // b*16 + h
    const int qtile = 31 - blockIdx.y;       // heavy-first
    const int b = bh >> 4, h = bh & 15;
    const int qbase = qtile * 64;
    const int wq = qbase + w * 16;

    const bf16* qkb = qk + (size_t)b * SEQ * 2048;
    const bf16* vb  = vtg + (size_t)bh * 64 * SEQ;

    // Q fragment (B-operand), scale 1/8 folded in (exact in bf16: pow2)
    bf16x8 q_lo, q_hi;
    {
        const bf16* qp = qkb + (size_t)(wq + l15) * 2048 + h * 64 + quad * 8;
        bf16x8 lo = *(const bf16x8*)qp;
        bf16x8 hi = *(const bf16x8*)(qp + 32);
#pragma unroll
        for (int i = 0; i < 8; ++i) {
            q_lo[i] = (bf16)((float)lo[i] * 0.125f);
            q_hi[i] = (bf16)((float)hi[i] * 0.125f);
        }
    }

    f32x4 o[4] = {};
    float mi = -1e30f, li = 0.f;

    const int kr0 = tid >> 3;  // 0..31
    const int ksg = tid & 7;   // 0..7 (16B chunks)

    const int nkt = qtile + 1;
    for (int kt = 0; kt < nkt; ++kt) {
        const int k0 = kt * 64;
        __syncthreads();
#pragma unroll
        for (int half = 0; half < 2; ++half) {
            const int kr = kr0 + half * 32;
            *(bf16x8*)(Ks + kr * 72 + ksg * 8) =
                *(const bf16x8*)(qkb + (size_t)(k0 + kr) * 2048 + DM + h * 64 + ksg * 8);
            *(bf16x8*)(Vts + kr * 72 + ksg * 8) =
                *(const bf16x8*)(vb + (size_t)kr * SEQ + k0 + ksg * 8);
        }
        __syncthreads();

        if (k0 <= wq + 15) {
            // S^T: 4 key-tiles x 2 MFMA (d=0..31, 32..63)
            f32x4 s[4];
#pragma unroll
            for (int t = 0; t < 4; ++t) {
                const bf16* kp = Ks + (t * 16 + l15) * 72 + quad * 8;
                bf16x8 k_lo = *(const bf16x8*)kp;
                bf16x8 k_hi = *(const bf16x8*)(kp + 32);
                f32x4 z = {};
                z = MFMA16(k_lo, q_lo, z);
                z = MFMA16(k_hi, q_hi, z);
                s[t] = z;
            }
            const int qg = wq + l15;
            if (k0 + 63 > wq) {  // diagonal tiles only
#pragma unroll
                for (int t = 0; t < 4; ++t)
#pragma unroll
                    for (int r = 0; r < 4; ++r)
                        if (k0 + t * 16 + quad * 4 + r > qg) s[t][r] = -1e30f;
            }
            // row max (q = l15), local + cross-quad
            float mx = s[0][0];
#pragma unroll
            for (int t = 0; t < 4; ++t)
#pragma unroll
                for (int r = 0; r < 4; ++r) mx = fmaxf(mx, s[t][r]);
            mx = fmaxf(mx, __shfl_xor(mx, 16));
            mx = fmaxf(mx, __shfl_xor(mx, 32));
            const float mnew = fmaxf(mi, mx);
            const float alpha = __expf(mi - mnew);
            mi = mnew;

            float rsum = 0.f;
            bf16x4v pb[4];
#pragma unroll
            for (int t = 0; t < 4; ++t)
#pragma unroll
                for (int r = 0; r < 4; ++r) {
                    float p = __expf(s[t][r] - mnew);
                    rsum += p;
                    pb[t][r] = (bf16)p;
                }
            rsum += __shfl_xor(rsum, 16);
            rsum += __shfl_xor(rsum, 32);
            li = li * alpha + rsum;
#pragma unroll
            for (int dt = 0; dt < 4; ++dt)
#pragma unroll
                for (int r = 0; r < 4; ++r) o[dt][r] *= alpha;

            bf16* P = &Pt[w][0];
#pragma unroll
            for (int t = 0; t < 4; ++t)
                *(bf16x4v*)(P + l15 * 72 + t * 16 + quad * 4) = pb[t];
            asm volatile("s_waitcnt lgkmcnt(0)" ::: "memory");

            bf16x8 pf0 = *(const bf16x8*)(P + l15 * 72 + quad * 8);
            bf16x8 pf1 = *(const bf16x8*)(P + l15 * 72 + 32 + quad * 8);
#pragma unroll
            for (int dt = 0; dt < 4; ++dt) {
                const bf16* vp = Vts + (dt * 16 + l15) * 72 + quad * 8;
                bf16x8 v0 = *(const bf16x8*)vp;
                bf16x8 v1 = *(const bf16x8*)(vp + 32);
                o[dt] = MFMA16(v0, pf0, o[dt]);
                o[dt] = MFMA16(v1, pf1, o[dt]);
            }
        }
    }

    // O^T lane layout: d = dt*16 + quad*4 + r, q = l15
    const float inv = 1.f / li;
    bf16* aop = ao + (size_t)(b * SEQ + wq + l15) * DM + h * 64;
#pragma unroll
    for (int dt = 0; dt < 4; ++dt) {
        bf16x4v ov;
#pragma unroll
        for (int r = 0; r < 4; ++r) ov[r] = (bf16)(o[dt][r] * inv);
        *(bf16x4v*)(aop + dt * 16 + quad * 4) = ov;
    }
}

// ---------------------------------------------------------------------------
extern "C" void kernel_launch(void* const* d_in, const int* in_sizes, int n_in,
                              void* d_out, int out_size, void* d_ws, size_t ws_size,
                              hipStream_t stream) {
    const float* X    = (const float*)d_in[0];
    const float* Wqkv = (const float*)d_in[1];
    const float* Wout = (const float*)d_in[2];
    float* out = (float*)d_out;

    const int M = 2 * SEQ;  // 4096
    const size_t nX    = (size_t)M * DM;       // 4M
    const size_t nWqkv = (size_t)3 * DM * DM;  // 3M
    const size_t nWout = (size_t)DM * DM;      // 1M
    const size_t nQK   = (size_t)M * 2 * DM;   // 8M
    const size_t nVT   = (size_t)2 * DM * SEQ; // 4M
    const size_t nAO   = (size_t)M * DM;       // 4M

    if (ws_size < (nX + nWqkv + nWout + nQK + nVT + nAO) * sizeof(bf16)) return;

    bf16* Xb    = (bf16*)d_ws;
    bf16* Wqkvb = Xb + nX;
    bf16* Woutb = Wqkvb + nWqkv;
    bf16* qkbuf = Woutb + nWout;
    bf16* vtg   = qkbuf + nQK;
    bf16* ao    = vtg + nVT;

    cvt_bf16<<<dim3((int)(nX / 4 / 256)),    256, 0, stream>>>(X,    Xb,    (int)(nX / 4));
    cvt_bf16<<<dim3((int)(nWqkv / 4 / 256)), 256, 0, stream>>>(Wqkv, Wqkvb, (int)(nWqkv / 4));
    cvt_bf16<<<dim3((int)(nWout / 4 / 256)), 256, 0, stream>>>(Wout, Woutb, (int)(nWout / 4));

    gemm_qkv<<<dim3(3 * DM / 128, M / 128), 256, 0, stream>>>(Xb, Wqkvb, qkbuf, vtg);
    attn_fwd<<<dim3(2 * NH, SEQ / 64), 256, 0, stream>>>(qkbuf, vtg, ao);
    gemm_nt<float><<<dim3(DM / 128, M / 128), 256, 0, stream>>>(ao, Woutb, out, M, DM, DM);
}